// Round 1
// baseline (916.995 us; speedup 1.0000x reference)
//
#include <hip/hip_runtime.h>

#define B_ 2
#define T_ 2048
#define H_ 16
#define D_ 128
#define DM_ 2048
#define CL_ 2048
#define KV_ 4096

typedef __attribute__((ext_vector_type(8))) short short8;
typedef __attribute__((ext_vector_type(4))) float f32x4;
typedef unsigned short u16;

__device__ __forceinline__ u16 f2bf(float f) {
    unsigned u = __float_as_uint(f);
    u += 0x7FFFu + ((u >> 16) & 1u);   // RNE to bf16
    return (u16)(u >> 16);
}

__device__ __forceinline__ void gload16(const void* g, void* l) {
    __builtin_amdgcn_global_load_lds((__attribute__((address_space(1))) const void*)g,
                                     (__attribute__((address_space(3))) void*)l, 16, 0, 0);
}

// ---------------- conversions ----------------

__global__ void cvt4(const float* __restrict__ src, u16* __restrict__ dst, int n4) {
    int i = blockIdx.x * 256 + threadIdx.x;
    if (i >= n4) return;
    const float4 v = *(const float4*)(src + (long)i * 4);
    ushort4 o;
    o.x = f2bf(v.x); o.y = f2bf(v.y); o.z = f2bf(v.z); o.w = f2bf(v.w);
    *(ushort4*)(dst + (long)i * 4) = o;
}

// cache_k f32 [bh][s(2048)][d] -> Kb bf16 [bh][s within 4096][d]
__global__ void cvt_cachek(const float* __restrict__ ck, u16* __restrict__ Kb) {
    long e = ((long)blockIdx.x * 256 + threadIdx.x) * 4;
    int bh = (int)(e >> 18);          // 2048*128 = 262144
    int rem = (int)(e & 262143);
    const float4 v = *(const float4*)(ck + e);
    ushort4 o;
    o.x = f2bf(v.x); o.y = f2bf(v.y); o.z = f2bf(v.z); o.w = f2bf(v.w);
    *(ushort4*)(Kb + (long)bh * (KV_ * D_) + rem) = o;
}

// cache_v f32 [bh][s][d] (s<2048) + Vn bf16 [bh][t][d] -> Vt bf16 [bh][d][s 0..4095]
__global__ void transpose_v(const float* __restrict__ cv, const u16* __restrict__ Vn,
                            u16* __restrict__ Vt) {
    __shared__ __align__(16) u16 tile[64][132];
    const int tid = threadIdx.x;
    const int bh = blockIdx.x >> 6;
    const int s0 = (blockIdx.x & 63) * 64;
    if (s0 < CL_) {
#pragma unroll
        for (int j = 0; j < 8; ++j) {
            int c = tid + j * 256;            // 2048 chunks of 4
            int sl = c >> 5, d0 = (c & 31) * 4;
            const float4 v = *(const float4*)(cv + ((long)bh * CL_ + s0 + sl) * D_ + d0);
            ushort4 o;
            o.x = f2bf(v.x); o.y = f2bf(v.y); o.z = f2bf(v.z); o.w = f2bf(v.w);
            *(ushort4*)&tile[sl][d0] = o;
        }
    } else {
#pragma unroll
        for (int j = 0; j < 8; ++j) {
            int c = tid + j * 256;
            int sl = c >> 5, d0 = (c & 31) * 4;
            ushort4 o = *(const ushort4*)(Vn + ((long)bh * T_ + s0 - CL_ + sl) * D_ + d0);
            *(ushort4*)&tile[sl][d0] = o;
        }
    }
    __syncthreads();
#pragma unroll
    for (int j = 0; j < 8; ++j) {
        int c = tid + j * 256;
        int d = c >> 4, sl0 = (c & 15) * 4;
        ushort4 o;
        o.x = tile[sl0 + 0][d]; o.y = tile[sl0 + 1][d];
        o.z = tile[sl0 + 2][d]; o.w = tile[sl0 + 3][d];
        *(ushort4*)(Vt + ((long)bh * D_ + d) * KV_ + s0 + sl0) = o;
    }
}

// ---------------- GEMM: C = A(MxK) * Bt(NxK)^T, bf16 in, fused epilogues ----------------
// MODE 0: qkv projection -> scatter to Qb (scaled), Kb[2048:], Vn
// MODE 1: out projection -> fp32 Out

template <int MODE>
__global__ void gemm_bt(const u16* __restrict__ A, const u16* __restrict__ Bt,
                        int K,
                        u16* __restrict__ Qb, u16* __restrict__ Kb,
                        u16* __restrict__ Vn, float* __restrict__ Out) {
    __shared__ __align__(16) char A_lds[128 * 128];  // [128 rows][64 k] bf16
    __shared__ __align__(16) char B_lds[128 * 128];

    const int tid = threadIdx.x;
    const int w = tid >> 6, l = tid & 63;
    const int wm = w >> 1, wn = w & 1;
    const int lg = l >> 4, lc = l & 15;
    const long m0 = (long)blockIdx.y * 128, n0 = (long)blockIdx.x * 128;

    f32x4 acc[4][4] = {};

    const char* Ab = (const char*)A + m0 * (K * 2);
    const char* Bb = (const char*)Bt + n0 * (K * 2);

    for (int k0 = 0; k0 < K; k0 += 64) {
#pragma unroll
        for (int j = 0; j < 4; ++j) {
            int o = ((w * 4 + j) << 10) + l * 16;
            int row = o >> 7, col = o & 127;
            gload16(Ab + (long)row * (K * 2) + k0 * 2 + col, A_lds + ((w * 4 + j) << 10));
            gload16(Bb + (long)row * (K * 2) + k0 * 2 + col, B_lds + ((w * 4 + j) << 10));
        }
        __syncthreads();
#pragma unroll
        for (int kk = 0; kk < 64; kk += 32) {
            short8 a[4], b[4];
#pragma unroll
            for (int f = 0; f < 4; ++f) {
                a[f] = *(const short8*)(A_lds + (wm * 64 + f * 16 + lc) * 128 + (kk + lg * 8) * 2);
                b[f] = *(const short8*)(B_lds + (wn * 64 + f * 16 + lc) * 128 + (kk + lg * 8) * 2);
            }
#pragma unroll
            for (int mf = 0; mf < 4; ++mf)
#pragma unroll
                for (int nf = 0; nf < 4; ++nf)
                    acc[mf][nf] = __builtin_amdgcn_mfma_f32_16x16x32_bf16(a[mf], b[nf], acc[mf][nf], 0, 0, 0);
        }
        __syncthreads();
    }

    const float qscale = 0.088388347648318447f;  // 128^-0.5
#pragma unroll
    for (int mf = 0; mf < 4; ++mf) {
#pragma unroll
        for (int nf = 0; nf < 4; ++nf) {
            int mbase = (int)m0 + wm * 64 + mf * 16 + lg * 4;
            int n = (int)n0 + wn * 64 + nf * 16 + lc;
#pragma unroll
            for (int r = 0; r < 4; ++r) {
                float c = acc[mf][nf][r];
                int m = mbase + r;
                if (MODE == 0) {
                    int b = m >> 11, t = m & 2047;
                    int sec = n >> 11, f = n & 2047;
                    int h = f >> 7, d = f & 127;
                    long bh = b * H_ + h;
                    if (sec == 0)      Qb[(bh * T_ + t) * D_ + d] = f2bf(c * qscale);
                    else if (sec == 1) Kb[(bh * KV_ + CL_ + t) * D_ + d] = f2bf(c);
                    else               Vn[(bh * T_ + t) * D_ + d] = f2bf(c);
                } else {
                    Out[(long)m * DM_ + n] = c;
                }
            }
        }
    }
}

// ---------------- flash attention ----------------
// grid: [bh(32) x qtile(32)], 256 threads = 4 waves, wave = 16 q rows
// K_lds [64 s][128 d] bf16, XOR-swizzled rows; V_lds [128 d][64 s] bf16, swizzled

__global__ void attn_fwd(const u16* __restrict__ Qb, const u16* __restrict__ Kb,
                         const u16* __restrict__ Vt, u16* __restrict__ Yb) {
    __shared__ __align__(16) char K_lds[16384];
    __shared__ __align__(16) char V_lds[16384];
    __shared__ __align__(16) u16 P_lds[4 * 16 * 72];  // per-wave 16 rows x stride 72

    const int tid = threadIdx.x;
    const int w = tid >> 6, l = tid & 63;
    const int lg = l >> 4, lc = l & 15;
    const int bh = blockIdx.x >> 5;
    const int q0 = (blockIdx.x & 31) * 64;
    const int trow0 = q0 + w * 16;

    short8 qf[4];
    const u16* qp = Qb + ((long)bh * T_ + trow0 + lc) * D_;
#pragma unroll
    for (int ks = 0; ks < 4; ++ks) qf[ks] = *(const short8*)(qp + ks * 32 + lg * 8);

    f32x4 oacc[8] = {};
    float mrun[4] = {-1e38f, -1e38f, -1e38f, -1e38f};
    float lrun[4] = {0.f, 0.f, 0.f, 0.f};

    const char* kb = (const char*)Kb + (long)bh * KV_ * 256;
    const char* vb = (const char*)Vt + (long)bh * D_ * 8192;
    u16* pw = P_lds + w * (16 * 72);

    const int sEnd = q0 + CL_;  // last (triangular) tile start
    for (int s0 = 0; s0 <= sEnd; s0 += 64) {
        // stage K tile (rows 256B) and V^T tile (rows 128B), pre-swizzled source
#pragma unroll
        for (int j = 0; j < 4; ++j) {
            int o = ((w * 4 + j) << 10) + l * 16;
            int s = o >> 8;
            gload16(kb + (long)s0 * 256 + (o ^ ((s & 7) << 4)), K_lds + ((w * 4 + j) << 10));
            int d = o >> 7;
            int so = (o ^ ((d & 7) << 4)) & 127;
            gload16(vb + (long)d * 8192 + s0 * 2 + so, V_lds + ((w * 4 + j) << 10));
        }
        __syncthreads();

        // S = Q K^T  (16 q rows x 64 s cols per wave)
        f32x4 sa[4] = {};
#pragma unroll
        for (int nf = 0; nf < 4; ++nf) {
            int srow = nf * 16 + lc;
            int sb = srow * 256, sw = (srow & 7) << 4;
#pragma unroll
            for (int ks = 0; ks < 4; ++ks) {
                short8 kf = *(const short8*)(K_lds + ((sb + (ks * 32 + lg * 8) * 2) ^ sw));
                sa[nf] = __builtin_amdgcn_mfma_f32_16x16x32_bf16(qf[ks], kf, sa[nf], 0, 0, 0);
            }
        }

        if (s0 + 64 > sEnd) {  // triangular tile
#pragma unroll
            for (int nf = 0; nf < 4; ++nf) {
                int scol = s0 + nf * 16 + lc;
#pragma unroll
                for (int r = 0; r < 4; ++r)
                    if (scol > trow0 + lg * 4 + r + CL_) sa[nf][r] = -3e38f;
            }
        }

        // online softmax (row stats across the 16 lanes of each group)
        float scl[4];
#pragma unroll
        for (int r = 0; r < 4; ++r) {
            float tm = fmaxf(fmaxf(sa[0][r], sa[1][r]), fmaxf(sa[2][r], sa[3][r]));
            tm = fmaxf(tm, __shfl_xor(tm, 1));
            tm = fmaxf(tm, __shfl_xor(tm, 2));
            tm = fmaxf(tm, __shfl_xor(tm, 4));
            tm = fmaxf(tm, __shfl_xor(tm, 8));
            float mnew = fmaxf(mrun[r], tm);
            scl[r] = __expf(mrun[r] - mnew);
            mrun[r] = mnew;
        }
#pragma unroll
        for (int nf = 0; nf < 4; ++nf)
#pragma unroll
            for (int r = 0; r < 4; ++r) sa[nf][r] = __expf(sa[nf][r] - mrun[r]);
#pragma unroll
        for (int r = 0; r < 4; ++r) {
            float ts = sa[0][r] + sa[1][r] + sa[2][r] + sa[3][r];
            ts += __shfl_xor(ts, 1);
            ts += __shfl_xor(ts, 2);
            ts += __shfl_xor(ts, 4);
            ts += __shfl_xor(ts, 8);
            lrun[r] = lrun[r] * scl[r] + ts;
        }
#pragma unroll
        for (int n = 0; n < 8; ++n)
#pragma unroll
            for (int r = 0; r < 4; ++r) oacc[n][r] *= scl[r];

        // P (C-layout) -> LDS -> A-layout fragments
#pragma unroll
        for (int nf = 0; nf < 4; ++nf)
#pragma unroll
            for (int r = 0; r < 4; ++r)
                pw[(lg * 4 + r) * 72 + nf * 16 + lc] = f2bf(sa[nf][r]);

#pragma unroll
        for (int ks = 0; ks < 2; ++ks) {
            short8 pf = *(const short8*)(pw + lc * 72 + ks * 32 + lg * 8);
#pragma unroll
            for (int n = 0; n < 8; ++n) {
                int d = n * 16 + lc;
                short8 vf = *(const short8*)(V_lds + ((d * 128 + (ks * 32 + lg * 8) * 2) ^ ((d & 7) << 4)));
                oacc[n] = __builtin_amdgcn_mfma_f32_16x16x32_bf16(pf, vf, oacc[n], 0, 0, 0);
            }
        }
        __syncthreads();
    }

    const int b = bh >> 4, h = bh & 15;
    float inv[4];
#pragma unroll
    for (int r = 0; r < 4; ++r) inv[r] = 1.0f / lrun[r];
#pragma unroll
    for (int n = 0; n < 8; ++n)
#pragma unroll
        for (int r = 0; r < 4; ++r) {
            int t = trow0 + lg * 4 + r;
            int c = h * D_ + n * 16 + lc;
            Yb[((long)b * T_ + t) * DM_ + c] = f2bf(oacc[n][r] * inv[r]);
        }
}

// ---------------- launch ----------------

extern "C" void kernel_launch(void* const* d_in, const int* in_sizes, int n_in,
                              void* d_out, int out_size, void* d_ws, size_t ws_size,
                              hipStream_t stream) {
    const float* x    = (const float*)d_in[0];
    const float* Wqkv = (const float*)d_in[1];
    const float* Wpr  = (const float*)d_in[2];
    const float* cK   = (const float*)d_in[3];
    const float* cV   = (const float*)d_in[4];
    float* out = (float*)d_out;

    char* p = (char*)d_ws;
    auto take = [&](long elems) { u16* r = (u16*)p; p += ((elems * 2 + 255) & ~255L); return r; };
    u16* xb  = take((long)B_ * T_ * DM_);        // x bf16 [4096][2048]
    u16* wqb = take((long)3 * DM_ * DM_);        // Wqkv bf16 [6144][2048]
    u16* wpb = take((long)DM_ * DM_);            // Wproj bf16 [2048][2048]
    u16* Qb  = take((long)B_ * H_ * T_ * D_);    // [bh][t][d], pre-scaled
    u16* Kb  = take((long)B_ * H_ * KV_ * D_);   // [bh][s(4096)][d]
    u16* Vt  = take((long)B_ * H_ * KV_ * D_);   // [bh][d][s(4096)]
    u16* Vn  = take((long)B_ * H_ * T_ * D_);    // new V [bh][t][d]
    u16* Yb  = take((long)B_ * T_ * DM_);        // attn out bf16 [4096][2048]

    cvt4<<<(B_ * T_ * DM_ / 4 + 255) / 256, 256, 0, stream>>>(x, xb, B_ * T_ * DM_ / 4);
    cvt4<<<(3 * DM_ * DM_ / 4 + 255) / 256, 256, 0, stream>>>(Wqkv, wqb, 3 * DM_ * DM_ / 4);
    cvt4<<<(DM_ * DM_ / 4 + 255) / 256, 256, 0, stream>>>(Wpr, wpb, DM_ * DM_ / 4);
    cvt_cachek<<<(B_ * H_ * CL_ * D_ / 4) / 256, 256, 0, stream>>>(cK, Kb);

    gemm_bt<0><<<dim3(48, 32), 256, 0, stream>>>(xb, wqb, 2048, Qb, Kb, Vn, nullptr);
    transpose_v<<<B_ * H_ * (KV_ / 64), 256, 0, stream>>>(cV, Vn, Vt);
    attn_fwd<<<B_ * H_ * (T_ / 64), 256, 0, stream>>>(Qb, Kb, Vt, Yb);
    gemm_bt<1><<<dim3(16, 32), 256, 0, stream>>>(Yb, wpb, 2048, nullptr, nullptr, nullptr, out);
}